// Round 3
// baseline (438.703 us; speedup 1.0000x reference)
//
#include <hip/hip_runtime.h>

namespace {
constexpr int NN = 100000;
constexpr int NE = 600000;
constexpr int H  = 128;
constexpr int SCAN_B = 256;
constexpr int NBLK_SCAN = (NN + SCAN_B - 1) / SCAN_B;  // 391

__global__ __launch_bounds__(256) void write_marker(float* __restrict__ out,
                                                    int n, float val) {
  int i = blockIdx.x * 256 + threadIdx.x;
  if (i < n) out[i] = val;
}

// ---------------- bottom-tier fallback (atomic path, verified) ----------------

__global__ __launch_bounds__(256) void zero_f4(float4* __restrict__ p, int n4) {
  int i = blockIdx.x * 256 + threadIdx.x;
  if (i < n4) p[i] = float4{0.f, 0.f, 0.f, 0.f};
}

__global__ __launch_bounds__(256) void scatter_l1(
    const int* __restrict__ src, const int* __restrict__ dst,
    const int* __restrict__ node_id, const float* __restrict__ embed,
    const float* __restrict__ norm, float* __restrict__ agg) {
  int idx = blockIdx.x * 256 + threadIdx.x;
  int e = idx >> 5;
  if (e >= NE) return;
  int c = (idx & 31) << 2;
  int s = src[e];
  float nrm = norm[s];
  const float4 v = *reinterpret_cast<const float4*>(embed + (size_t)node_id[s] * H + c);
  float* o = agg + (size_t)dst[e] * H + c;
  atomicAdd(o + 0, v.x * nrm);
  atomicAdd(o + 1, v.y * nrm);
  atomicAdd(o + 2, v.z * nrm);
  atomicAdd(o + 3, v.w * nrm);
}

__global__ __launch_bounds__(256) void scatter_l2(
    const int* __restrict__ src, const int* __restrict__ dst,
    const float* __restrict__ h1, const float* __restrict__ norm,
    float* __restrict__ agg) {
  int idx = blockIdx.x * 256 + threadIdx.x;
  int e = idx >> 5;
  if (e >= NE) return;
  int c = (idx & 31) << 2;
  int s = src[e];
  float nrm = norm[s];
  const float4 v = *reinterpret_cast<const float4*>(h1 + (size_t)s * H + c);
  float* o = agg + (size_t)dst[e] * H + c;
  atomicAdd(o + 0, v.x * nrm);
  atomicAdd(o + 1, v.y * nrm);
  atomicAdd(o + 2, v.z * nrm);
  atomicAdd(o + 3, v.w * nrm);
}

__global__ __launch_bounds__(128) void row_gemm_act(
    const float* __restrict__ agg, const float* __restrict__ W,
    const float* __restrict__ norm, const float* __restrict__ bias,
    float* __restrict__ out) {
  __shared__ float hs[H];
  const int row = blockIdx.x, j = threadIdx.x;
  hs[j] = agg[(size_t)row * H + j];
  __syncthreads();
  float acc = 0.f;
#pragma unroll
  for (int k = 0; k < H; ++k) acc += hs[k] * W[k * H + j];
  float v = acc * norm[row] + bias[j];
  v = v > 0.f ? v : 0.2f * v;
  out[(size_t)row * H + j] = v;
}

// ---------------- CSR build ----------------

__global__ __launch_bounds__(256) void zero_int(int* __restrict__ p, int n) {
  int i = blockIdx.x * 256 + threadIdx.x;
  if (i < n) p[i] = 0;
}

__global__ __launch_bounds__(256) void hist_dst(const int* __restrict__ dst,
                                                int* __restrict__ deg) {
  int e = blockIdx.x * 256 + threadIdx.x;
  if (e < NE) atomicAdd(&deg[dst[e]], 1);
}

__global__ __launch_bounds__(SCAN_B) void scan1(const int* __restrict__ deg,
                                                int* __restrict__ offs,
                                                int* __restrict__ bsums) {
  __shared__ int sh[SCAN_B];
  const int t = threadIdx.x;
  const int gid = blockIdx.x * SCAN_B + t;
  int v = (gid < NN) ? deg[gid] : 0;
  sh[t] = v;
  __syncthreads();
  for (int d = 1; d < SCAN_B; d <<= 1) {
    int add = (t >= d) ? sh[t - d] : 0;
    __syncthreads();
    sh[t] += add;
    __syncthreads();
  }
  if (gid < NN) offs[gid] = sh[t] - v;
  if (t == SCAN_B - 1) bsums[blockIdx.x] = sh[t];
}

__global__ __launch_bounds__(512) void scan2(int* __restrict__ bsums) {
  __shared__ int sh[512];
  const int t = threadIdx.x;
  int v = (t < NBLK_SCAN) ? bsums[t] : 0;
  sh[t] = v;
  __syncthreads();
  for (int d = 1; d < 512; d <<= 1) {
    int add = (t >= d) ? sh[t - d] : 0;
    __syncthreads();
    sh[t] += add;
    __syncthreads();
  }
  if (t < NBLK_SCAN) bsums[t] = sh[t] - v;
}

// finalize offs AND seed cnt = offs (fill uses cnt as running cursor)
__global__ __launch_bounds__(256) void scan3(int* __restrict__ offs,
                                             const int* __restrict__ bsums,
                                             int* __restrict__ cnt) {
  int gid = blockIdx.x * 256 + threadIdx.x;
  if (gid < NN) {
    int v = offs[gid] + bsums[blockIdx.x];
    offs[gid] = v;
    cnt[gid] = v;
  }
  if (gid == 0) offs[NN] = NE;
}

template <bool WITH_REC>
__global__ __launch_bounds__(256) void fill_csr(
    const int* __restrict__ src, const int* __restrict__ dst,
    const int* __restrict__ node_id, const float* __restrict__ norm,
    int* __restrict__ cnt, int* __restrict__ csr2, int2* __restrict__ rec1) {
  int e = blockIdx.x * 256 + threadIdx.x;
  if (e >= NE) return;
  int d = dst[e];
  int s = src[e];
  int pos = atomicAdd(&cnt[d], 1);
  csr2[pos] = s;
  if (WITH_REC) rec1[pos] = make_int2(node_id[s], __float_as_int(norm[s]));
}

// ---------------- gathers (no atomics) ----------------

// L1: per-edge record {row, nrm}; 32 lanes per node, float4/lane.
__global__ __launch_bounds__(256) void gather_rec(
    const int* __restrict__ offs, const int2* __restrict__ rec,
    const float* __restrict__ h, float* __restrict__ agg) {
  const int node = blockIdx.x * 8 + (threadIdx.x >> 5);
  const int c = (threadIdx.x & 31) << 2;
  const int beg = offs[node];
  const int end = offs[node + 1];
  float4 acc{0.f, 0.f, 0.f, 0.f}, acc2{0.f, 0.f, 0.f, 0.f};
  int i = beg;
  for (; i + 2 <= end; i += 2) {
    int2 ra = rec[i], rb = rec[i + 1];
    const float4 va = *reinterpret_cast<const float4*>(h + (size_t)ra.x * H + c);
    const float4 vb = *reinterpret_cast<const float4*>(h + (size_t)rb.x * H + c);
    float na = __int_as_float(ra.y), nb = __int_as_float(rb.y);
    acc.x += va.x * na;  acc.y += va.y * na;  acc.z += va.z * na;  acc.w += va.w * na;
    acc2.x += vb.x * nb; acc2.y += vb.y * nb; acc2.z += vb.z * nb; acc2.w += vb.w * nb;
  }
  if (i < end) {
    int2 ra = rec[i];
    const float4 va = *reinterpret_cast<const float4*>(h + (size_t)ra.x * H + c);
    float na = __int_as_float(ra.y);
    acc.x += va.x * na; acc.y += va.y * na; acc.z += va.z * na; acc.w += va.w * na;
  }
  acc.x += acc2.x; acc.y += acc2.y; acc.z += acc2.z; acc.w += acc2.w;
  *reinterpret_cast<float4*>(agg + (size_t)node * H + c) = acc;
}

// L2: h is pre-scaled by norm (h1n), so just sum rows.
__global__ __launch_bounds__(256) void gather_idx(
    const int* __restrict__ offs, const int* __restrict__ csr,
    const float* __restrict__ h, float* __restrict__ agg) {
  const int node = blockIdx.x * 8 + (threadIdx.x >> 5);
  const int c = (threadIdx.x & 31) << 2;
  const int beg = offs[node];
  const int end = offs[node + 1];
  float4 acc{0.f, 0.f, 0.f, 0.f}, acc2{0.f, 0.f, 0.f, 0.f};
  int i = beg;
  for (; i + 2 <= end; i += 2) {
    int r0 = csr[i], r1 = csr[i + 1];
    const float4 va = *reinterpret_cast<const float4*>(h + (size_t)r0 * H + c);
    const float4 vb = *reinterpret_cast<const float4*>(h + (size_t)r1 * H + c);
    acc.x += va.x;  acc.y += va.y;  acc.z += va.z;  acc.w += va.w;
    acc2.x += vb.x; acc2.y += vb.y; acc2.z += vb.z; acc2.w += vb.w;
  }
  if (i < end) {
    int r0 = csr[i];
    const float4 va = *reinterpret_cast<const float4*>(h + (size_t)r0 * H + c);
    acc.x += va.x; acc.y += va.y; acc.z += va.z; acc.w += va.w;
  }
  acc.x += acc2.x; acc.y += acc2.y; acc.z += acc2.z; acc.w += acc2.w;
  *reinterpret_cast<float4*>(agg + (size_t)node * H + c) = acc;
}

// mid-tier L1 gather (no records): loads node_id/norm per edge
__global__ __launch_bounds__(256) void gather_mid_l1(
    const int* __restrict__ offs, const int* __restrict__ csr,
    const int* __restrict__ node_id, const float* __restrict__ h,
    const float* __restrict__ norm, float* __restrict__ agg) {
  const int node = blockIdx.x * 8 + (threadIdx.x >> 5);
  const int c = (threadIdx.x & 31) << 2;
  const int beg = offs[node];
  const int end = offs[node + 1];
  float4 acc{0.f, 0.f, 0.f, 0.f};
  for (int i = beg; i < end; ++i) {
    int s = csr[i];
    float nrm = norm[s];
    const float4 v = *reinterpret_cast<const float4*>(h + (size_t)node_id[s] * H + c);
    acc.x += v.x * nrm; acc.y += v.y * nrm; acc.z += v.z * nrm; acc.w += v.w * nrm;
  }
  *reinterpret_cast<float4*>(agg + (size_t)node * H + c) = acc;
}

// ---------------- GEMM: 128 rows/block, 8x8 register tile, swizzled LDS ----------------

#define FMA4(ACC, S, W) \
  ACC.x += (S) * (W).x; ACC.y += (S) * (W).y; ACC.z += (S) * (W).z; ACC.w += (S) * (W).w;

// out[row] = LReLU((agg[row] @ W) * norm[row] + b) * (SCALE_OUT ? norm[row] : 1)
template <bool SCALE_OUT>
__global__ __launch_bounds__(256, 1) void gemm128_act(
    const float* __restrict__ agg, const float* __restrict__ W,
    const float* __restrict__ norm, const float* __restrict__ bias,
    float* __restrict__ out) {
  __shared__ float4 Wld[128 * 32];  // 64 KB, de-interleaved: [k][j8 + 16*b]
  __shared__ float4 As[128 * 32];   // 64 KB, XOR-swizzled: [row][k4 ^ (row&7)]
  const int t = threadIdx.x;
  const int rowBase = blockIdx.x * 128;

  const float4* W4 = reinterpret_cast<const float4*>(W);
#pragma unroll
  for (int i = 0; i < 16; ++i) {
    int g = t + i * 256;            // 0..4095
    int k = g >> 5, c4 = g & 31;    // c4 = 2*j8 + b
    int sc4 = (c4 >> 1) + ((c4 & 1) << 4);
    Wld[k * 32 + sc4] = W4[g];
  }
  const float4* A4 = reinterpret_cast<const float4*>(agg) + (size_t)rowBase * 32;
#pragma unroll
  for (int i = 0; i < 16; ++i) {
    int g = t + i * 256;
    int r = g >> 5, k4 = g & 31;
    float4 v = (rowBase + r < NN) ? A4[g] : float4{0.f, 0.f, 0.f, 0.f};
    As[r * 32 + (k4 ^ (r & 7))] = v;
  }
  __syncthreads();

  const int j8 = t & 15;   // col group of 8 (cols 8*j8 .. 8*j8+7)
  const int r0 = t >> 4;   // 0..15; rows r0 + 16*i
  float4 accA[8], accB[8];
#pragma unroll
  for (int i = 0; i < 8; ++i) {
    accA[i] = float4{0.f, 0.f, 0.f, 0.f};
    accB[i] = float4{0.f, 0.f, 0.f, 0.f};
  }

#pragma unroll 4
  for (int k4 = 0; k4 < 32; ++k4) {
    const int kb = k4 * 128;  // (4*k4) * 32
    float4 wa0 = Wld[kb + j8],       wb0 = Wld[kb + j8 + 16];
    float4 wa1 = Wld[kb + 32 + j8],  wb1 = Wld[kb + 32 + j8 + 16];
    float4 wa2 = Wld[kb + 64 + j8],  wb2 = Wld[kb + 64 + j8 + 16];
    float4 wa3 = Wld[kb + 96 + j8],  wb3 = Wld[kb + 96 + j8 + 16];
#pragma unroll
    for (int i = 0; i < 8; ++i) {
      const int row = r0 + 16 * i;
      float4 a = As[row * 32 + (k4 ^ (row & 7))];
      FMA4(accA[i], a.x, wa0) FMA4(accB[i], a.x, wb0)
      FMA4(accA[i], a.y, wa1) FMA4(accB[i], a.y, wb1)
      FMA4(accA[i], a.z, wa2) FMA4(accB[i], a.z, wb2)
      FMA4(accA[i], a.w, wa3) FMA4(accB[i], a.w, wb3)
    }
  }

  const float4 bv0 = reinterpret_cast<const float4*>(bias)[2 * j8];
  const float4 bv1 = reinterpret_cast<const float4*>(bias)[2 * j8 + 1];
#pragma unroll
  for (int i = 0; i < 8; ++i) {
    const int row = rowBase + r0 + 16 * i;
    if (row < NN) {
      const float nrm = norm[row];
      float4 o0, o1;
      o0.x = accA[i].x * nrm + bv0.x; o0.y = accA[i].y * nrm + bv0.y;
      o0.z = accA[i].z * nrm + bv0.z; o0.w = accA[i].w * nrm + bv0.w;
      o1.x = accB[i].x * nrm + bv1.x; o1.y = accB[i].y * nrm + bv1.y;
      o1.z = accB[i].z * nrm + bv1.z; o1.w = accB[i].w * nrm + bv1.w;
      o0.x = o0.x > 0.f ? o0.x : 0.2f * o0.x;
      o0.y = o0.y > 0.f ? o0.y : 0.2f * o0.y;
      o0.z = o0.z > 0.f ? o0.z : 0.2f * o0.z;
      o0.w = o0.w > 0.f ? o0.w : 0.2f * o0.w;
      o1.x = o1.x > 0.f ? o1.x : 0.2f * o1.x;
      o1.y = o1.y > 0.f ? o1.y : 0.2f * o1.y;
      o1.z = o1.z > 0.f ? o1.z : 0.2f * o1.z;
      o1.w = o1.w > 0.f ? o1.w : 0.2f * o1.w;
      if (SCALE_OUT) {
        o0.x *= nrm; o0.y *= nrm; o0.z *= nrm; o0.w *= nrm;
        o1.x *= nrm; o1.y *= nrm; o1.z *= nrm; o1.w *= nrm;
      }
      float4* op = reinterpret_cast<float4*>(out + (size_t)row * H + j8 * 8);
      op[0] = o0;
      op[1] = o1;
    }
  }
}

}  // namespace

extern "C" void kernel_launch(void* const* d_in, const int* in_sizes, int n_in,
                              void* d_out, int out_size, void* d_ws, size_t ws_size,
                              hipStream_t stream) {
  float* out = (float*)d_out;                 // OUTPUT IS FP32
  const int nElem = NN * H;                   // 12.8M
  const int mkBl  = (out_size + 255) / 256;

  bool order_ok =
      (n_in == 9 && in_sizes[0] == NN && in_sizes[1] == NE && in_sizes[2] == NE &&
       in_sizes[3] == NN && in_sizes[4] == NN * H && in_sizes[5] == H * H &&
       in_sizes[6] == H && in_sizes[7] == H * H && in_sizes[8] == H);
  if (!order_ok || out_size != nElem) {
    write_marker<<<mkBl, 256, 0, stream>>>(out, out_size,
                                           (out_size != nElem) ? 300.0f : 200.0f);
    return;
  }
  if (ws_size < (size_t)nElem * 4) {
    write_marker<<<mkBl, 256, 0, stream>>>(out, out_size,
                                           2.0f + (float)(ws_size >> 20));
    return;
  }

  const int* node_id = (const int*)d_in[0];
  const int* src     = (const int*)d_in[1];
  const int* dst     = (const int*)d_in[2];
  const float* norm  = (const float*)d_in[3];
  const float* embed = (const float*)d_in[4];
  const float* W1    = (const float*)d_in[5];
  const float* b1    = (const float*)d_in[6];
  const float* W2    = (const float*)d_in[7];
  const float* b2    = (const float*)d_in[8];

  float* agg = (float*)d_ws;                             // 51.2 MB
  float* h1n = out;                                      // d_out holds h1*norm
  int2* rec1 = (int2*)((char*)d_ws + (size_t)nElem * 4); // NE x 8B (8-aligned)
  int* csr2  = (int*)(rec1 + NE);                        // NE
  int* offs  = csr2 + NE;                                // NN+1
  int* cnt   = offs + (NN + 1);                          // NN
  int* bsums = cnt + NN;                                 // 512

  const size_t need_mid =
      (size_t)nElem * 4 + ((size_t)NE + (NN + 1) + NN + 512) * 4;        // ~54.4 MB
  const size_t need_full = need_mid + (size_t)NE * 8;                    // ~59.2 MB

  const int zeroNBl = (NN + 255) / 256;
  const int edgeBl  = (NE + 255) / 256;
  const int gemmBl  = (NN + 127) / 128;  // 782

  if (ws_size >= need_mid) {
    const bool full = (ws_size >= need_full);
    // layout shift for mid tier: rec1 unused; csr2 right after agg
    if (!full) {
      csr2  = (int*)((char*)d_ws + (size_t)nElem * 4);
      offs  = csr2 + NE;
      cnt   = offs + (NN + 1);
      bsums = cnt + NN;
    }

    // ---- build CSR by dst (shared by both layers) ----
    zero_int<<<zeroNBl, 256, 0, stream>>>(cnt, NN);
    hist_dst<<<edgeBl, 256, 0, stream>>>(dst, cnt);
    scan1<<<NBLK_SCAN, SCAN_B, 0, stream>>>(cnt, offs, bsums);
    scan2<<<1, 512, 0, stream>>>(bsums);
    scan3<<<NBLK_SCAN, 256, 0, stream>>>(offs, bsums, cnt);
    if (full)
      fill_csr<true><<<edgeBl, 256, 0, stream>>>(src, dst, node_id, norm, cnt, csr2, rec1);
    else
      fill_csr<false><<<edgeBl, 256, 0, stream>>>(src, dst, node_id, norm, cnt, csr2, nullptr);

    // ---- layer 1 ----
    if (full)
      gather_rec<<<NN / 8, 256, 0, stream>>>(offs, rec1, embed, agg);
    else
      gather_mid_l1<<<NN / 8, 256, 0, stream>>>(offs, csr2, node_id, embed, norm, agg);
    gemm128_act<true><<<gemmBl, 256, 0, stream>>>(agg, W1, norm, b1, h1n);

    // ---- layer 2 ----
    gather_idx<<<NN / 8, 256, 0, stream>>>(offs, csr2, h1n, agg);
    gemm128_act<false><<<gemmBl, 256, 0, stream>>>(agg, W2, norm, b2, out);
    return;
  }

  // ---- bottom-tier fallback: atomic path ----
  const int zeroBl = (nElem / 4 + 255) / 256;
  const int scatBl = (NE * 32 + 255) / 256;

  zero_f4<<<zeroBl, 256, 0, stream>>>((float4*)agg, nElem / 4);
  scatter_l1<<<scatBl, 256, 0, stream>>>(src, dst, node_id, embed, norm, agg);
  row_gemm_act<<<NN, 128, 0, stream>>>(agg, W1, norm, b1, out);

  zero_f4<<<zeroBl, 256, 0, stream>>>((float4*)agg, nElem / 4);
  scatter_l2<<<scatBl, 256, 0, stream>>>(src, dst, out, norm, agg);
  row_gemm_act<<<NN, 128, 0, stream>>>(agg, W2, norm, b2, out);
}

// Round 4
// 381.284 us; speedup vs baseline: 1.1506x; 1.1506x over previous
//
#include <hip/hip_runtime.h>

namespace {
constexpr int NN = 100000;
constexpr int NE = 600000;
constexpr int H  = 128;
constexpr int SCAN_B = 256;
constexpr int NBLK_SCAN = (NN + SCAN_B - 1) / SCAN_B;  // 391

__global__ __launch_bounds__(256) void write_marker(float* __restrict__ out,
                                                    int n, float val) {
  int i = blockIdx.x * 256 + threadIdx.x;
  if (i < n) out[i] = val;
}

// ---------------- bottom-tier fallback (atomic path, verified) ----------------

__global__ __launch_bounds__(256) void zero_f4(float4* __restrict__ p, int n4) {
  int i = blockIdx.x * 256 + threadIdx.x;
  if (i < n4) p[i] = float4{0.f, 0.f, 0.f, 0.f};
}

__global__ __launch_bounds__(256) void scatter_l1(
    const int* __restrict__ src, const int* __restrict__ dst,
    const int* __restrict__ node_id, const float* __restrict__ embed,
    const float* __restrict__ norm, float* __restrict__ agg) {
  int idx = blockIdx.x * 256 + threadIdx.x;
  int e = idx >> 5;
  if (e >= NE) return;
  int c = (idx & 31) << 2;
  int s = src[e];
  float nrm = norm[s];
  const float4 v = *reinterpret_cast<const float4*>(embed + (size_t)node_id[s] * H + c);
  float* o = agg + (size_t)dst[e] * H + c;
  atomicAdd(o + 0, v.x * nrm);
  atomicAdd(o + 1, v.y * nrm);
  atomicAdd(o + 2, v.z * nrm);
  atomicAdd(o + 3, v.w * nrm);
}

__global__ __launch_bounds__(256) void scatter_l2(
    const int* __restrict__ src, const int* __restrict__ dst,
    const float* __restrict__ h1, const float* __restrict__ norm,
    float* __restrict__ agg) {
  int idx = blockIdx.x * 256 + threadIdx.x;
  int e = idx >> 5;
  if (e >= NE) return;
  int c = (idx & 31) << 2;
  int s = src[e];
  float nrm = norm[s];
  const float4 v = *reinterpret_cast<const float4*>(h1 + (size_t)s * H + c);
  float* o = agg + (size_t)dst[e] * H + c;
  atomicAdd(o + 0, v.x * nrm);
  atomicAdd(o + 1, v.y * nrm);
  atomicAdd(o + 2, v.z * nrm);
  atomicAdd(o + 3, v.w * nrm);
}

__global__ __launch_bounds__(128) void row_gemm_act(
    const float* __restrict__ agg, const float* __restrict__ W,
    const float* __restrict__ norm, const float* __restrict__ bias,
    float* __restrict__ out) {
  __shared__ float hs[H];
  const int row = blockIdx.x, j = threadIdx.x;
  hs[j] = agg[(size_t)row * H + j];
  __syncthreads();
  float acc = 0.f;
#pragma unroll
  for (int k = 0; k < H; ++k) acc += hs[k] * W[k * H + j];
  float v = acc * norm[row] + bias[j];
  v = v > 0.f ? v : 0.2f * v;
  out[(size_t)row * H + j] = v;
}

// ---------------- CSR build ----------------

__global__ __launch_bounds__(256) void zero_int(int* __restrict__ p, int n) {
  int i = blockIdx.x * 256 + threadIdx.x;
  if (i < n) p[i] = 0;
}

__global__ __launch_bounds__(256) void hist_dst(const int* __restrict__ dst,
                                                int* __restrict__ deg) {
  int e = blockIdx.x * 256 + threadIdx.x;
  if (e < NE) atomicAdd(&deg[dst[e]], 1);
}

__global__ __launch_bounds__(SCAN_B) void scan1(const int* __restrict__ deg,
                                                int* __restrict__ offs,
                                                int* __restrict__ bsums) {
  __shared__ int sh[SCAN_B];
  const int t = threadIdx.x;
  const int gid = blockIdx.x * SCAN_B + t;
  int v = (gid < NN) ? deg[gid] : 0;
  sh[t] = v;
  __syncthreads();
  for (int d = 1; d < SCAN_B; d <<= 1) {
    int add = (t >= d) ? sh[t - d] : 0;
    __syncthreads();
    sh[t] += add;
    __syncthreads();
  }
  if (gid < NN) offs[gid] = sh[t] - v;
  if (t == SCAN_B - 1) bsums[blockIdx.x] = sh[t];
}

__global__ __launch_bounds__(512) void scan2(int* __restrict__ bsums) {
  __shared__ int sh[512];
  const int t = threadIdx.x;
  int v = (t < NBLK_SCAN) ? bsums[t] : 0;
  sh[t] = v;
  __syncthreads();
  for (int d = 1; d < 512; d <<= 1) {
    int add = (t >= d) ? sh[t - d] : 0;
    __syncthreads();
    sh[t] += add;
    __syncthreads();
  }
  if (t < NBLK_SCAN) bsums[t] = sh[t] - v;
}

// finalize offs AND seed cnt = offs (fill uses cnt as running cursor)
__global__ __launch_bounds__(256) void scan3(int* __restrict__ offs,
                                             const int* __restrict__ bsums,
                                             int* __restrict__ cnt) {
  int gid = blockIdx.x * 256 + threadIdx.x;
  if (gid < NN) {
    int v = offs[gid] + bsums[blockIdx.x];
    offs[gid] = v;
    cnt[gid] = v;
  }
  if (gid == 0) offs[NN] = NE;
}

template <bool WITH_REC>
__global__ __launch_bounds__(256) void fill_csr(
    const int* __restrict__ src, const int* __restrict__ dst,
    const int* __restrict__ node_id, const float* __restrict__ norm,
    int* __restrict__ cnt, int* __restrict__ csr2, int2* __restrict__ rec1) {
  int e = blockIdx.x * 256 + threadIdx.x;
  if (e >= NE) return;
  int d = dst[e];
  int s = src[e];
  int pos = atomicAdd(&cnt[d], 1);
  csr2[pos] = s;
  if (WITH_REC) rec1[pos] = make_int2(node_id[s], __float_as_int(norm[s]));
}

// ---------------- gathers (no atomics) ----------------

// L1: per-edge record {row, nrm}; 32 lanes per node, float4/lane.
__global__ __launch_bounds__(256) void gather_rec(
    const int* __restrict__ offs, const int2* __restrict__ rec,
    const float* __restrict__ h, float* __restrict__ agg) {
  const int node = blockIdx.x * 8 + (threadIdx.x >> 5);
  const int c = (threadIdx.x & 31) << 2;
  const int beg = offs[node];
  const int end = offs[node + 1];
  float4 acc{0.f, 0.f, 0.f, 0.f}, acc2{0.f, 0.f, 0.f, 0.f};
  int i = beg;
  for (; i + 2 <= end; i += 2) {
    int2 ra = rec[i], rb = rec[i + 1];
    const float4 va = *reinterpret_cast<const float4*>(h + (size_t)ra.x * H + c);
    const float4 vb = *reinterpret_cast<const float4*>(h + (size_t)rb.x * H + c);
    float na = __int_as_float(ra.y), nb = __int_as_float(rb.y);
    acc.x += va.x * na;  acc.y += va.y * na;  acc.z += va.z * na;  acc.w += va.w * na;
    acc2.x += vb.x * nb; acc2.y += vb.y * nb; acc2.z += vb.z * nb; acc2.w += vb.w * nb;
  }
  if (i < end) {
    int2 ra = rec[i];
    const float4 va = *reinterpret_cast<const float4*>(h + (size_t)ra.x * H + c);
    float na = __int_as_float(ra.y);
    acc.x += va.x * na; acc.y += va.y * na; acc.z += va.z * na; acc.w += va.w * na;
  }
  acc.x += acc2.x; acc.y += acc2.y; acc.z += acc2.z; acc.w += acc2.w;
  *reinterpret_cast<float4*>(agg + (size_t)node * H + c) = acc;
}

// L2: h is pre-scaled by norm (h1n), so just sum rows.
__global__ __launch_bounds__(256) void gather_idx(
    const int* __restrict__ offs, const int* __restrict__ csr,
    const float* __restrict__ h, float* __restrict__ agg) {
  const int node = blockIdx.x * 8 + (threadIdx.x >> 5);
  const int c = (threadIdx.x & 31) << 2;
  const int beg = offs[node];
  const int end = offs[node + 1];
  float4 acc{0.f, 0.f, 0.f, 0.f}, acc2{0.f, 0.f, 0.f, 0.f};
  int i = beg;
  for (; i + 2 <= end; i += 2) {
    int r0 = csr[i], r1 = csr[i + 1];
    const float4 va = *reinterpret_cast<const float4*>(h + (size_t)r0 * H + c);
    const float4 vb = *reinterpret_cast<const float4*>(h + (size_t)r1 * H + c);
    acc.x += va.x;  acc.y += va.y;  acc.z += va.z;  acc.w += va.w;
    acc2.x += vb.x; acc2.y += vb.y; acc2.z += vb.z; acc2.w += vb.w;
  }
  if (i < end) {
    int r0 = csr[i];
    const float4 va = *reinterpret_cast<const float4*>(h + (size_t)r0 * H + c);
    acc.x += va.x; acc.y += va.y; acc.z += va.z; acc.w += va.w;
  }
  acc.x += acc2.x; acc.y += acc2.y; acc.z += acc2.z; acc.w += acc2.w;
  *reinterpret_cast<float4*>(agg + (size_t)node * H + c) = acc;
}

// mid-tier L1 gather (no records): loads node_id/norm per edge
__global__ __launch_bounds__(256) void gather_mid_l1(
    const int* __restrict__ offs, const int* __restrict__ csr,
    const int* __restrict__ node_id, const float* __restrict__ h,
    const float* __restrict__ norm, float* __restrict__ agg) {
  const int node = blockIdx.x * 8 + (threadIdx.x >> 5);
  const int c = (threadIdx.x & 31) << 2;
  const int beg = offs[node];
  const int end = offs[node + 1];
  float4 acc{0.f, 0.f, 0.f, 0.f};
  for (int i = beg; i < end; ++i) {
    int s = csr[i];
    float nrm = norm[s];
    const float4 v = *reinterpret_cast<const float4*>(h + (size_t)node_id[s] * H + c);
    acc.x += v.x * nrm; acc.y += v.y * nrm; acc.z += v.z * nrm; acc.w += v.w * nrm;
  }
  *reinterpret_cast<float4*>(agg + (size_t)node * H + c) = acc;
}

// ---------------- GEMM v3: W-only in LDS (64 KB), A streamed from global ----------------
// 128 rows/block, 256 threads, 8x8 register tile. 64 KB LDS -> 2 blocks/CU,
// 2 waves/SIMD (vs v2's 128 KB -> 1 block/CU, 1 wave/SIMD, VALUBusy 23%).
// Per k4 per wave: 8 global float4 A-loads (16-lane same-address merged, L1/L2
// resident) + 8 ds_read_b128 W (96 LDS cyc) vs 512 VALU cyc -> VALU-bound.

#define FMA4(ACC, S, W) \
  ACC.x += (S) * (W).x; ACC.y += (S) * (W).y; ACC.z += (S) * (W).z; ACC.w += (S) * (W).w;

// out[row] = LReLU((agg[row] @ W) * norm[row] + b) * (SCALE_OUT ? norm[row] : 1)
template <bool SCALE_OUT>
__global__ __launch_bounds__(256, 2) void gemm_v3(
    const float* __restrict__ agg, const float* __restrict__ W,
    const float* __restrict__ norm, const float* __restrict__ bias,
    float* __restrict__ out) {
  __shared__ float4 Wld[128 * 32];  // 64 KB, de-interleaved: [k][j8 + 16*b]
  const int t = threadIdx.x;
  const int rowBase = blockIdx.x * 128;

  const float4* W4 = reinterpret_cast<const float4*>(W);
#pragma unroll
  for (int i = 0; i < 16; ++i) {
    int g = t + i * 256;            // 0..4095
    int k = g >> 5, c4 = g & 31;    // c4 = 2*j8 + b
    int sc4 = (c4 >> 1) + ((c4 & 1) << 4);
    Wld[k * 32 + sc4] = W4[g];
  }
  __syncthreads();

  const int j8 = t & 15;   // col group of 8 (cols 8*j8 .. 8*j8+7)
  const int r0 = t >> 4;   // 0..15; rows r0 + 16*i
  const float4* A4 = reinterpret_cast<const float4*>(agg) + (size_t)rowBase * 32;

  float4 accA[8], accB[8];
#pragma unroll
  for (int i = 0; i < 8; ++i) {
    accA[i] = float4{0.f, 0.f, 0.f, 0.f};
    accB[i] = float4{0.f, 0.f, 0.f, 0.f};
  }

  // NOTE: last block reads A rows up to 100095 (> NN); those land inside the
  // allocated workspace (CSR arrays follow agg) so reads are safe; the
  // corresponding outputs are guarded at the store.
#pragma unroll 2
  for (int k4 = 0; k4 < 32; ++k4) {
    float4 a[8];
#pragma unroll
    for (int i = 0; i < 8; ++i) a[i] = A4[(r0 + 16 * i) * 32 + k4];
    const int kb = k4 * 128;  // (4*k4) * 32
    float4 wa0 = Wld[kb + j8],       wb0 = Wld[kb + j8 + 16];
    float4 wa1 = Wld[kb + 32 + j8],  wb1 = Wld[kb + 32 + j8 + 16];
    float4 wa2 = Wld[kb + 64 + j8],  wb2 = Wld[kb + 64 + j8 + 16];
    float4 wa3 = Wld[kb + 96 + j8],  wb3 = Wld[kb + 96 + j8 + 16];
#pragma unroll
    for (int i = 0; i < 8; ++i) {
      FMA4(accA[i], a[i].x, wa0) FMA4(accB[i], a[i].x, wb0)
      FMA4(accA[i], a[i].y, wa1) FMA4(accB[i], a[i].y, wb1)
      FMA4(accA[i], a[i].z, wa2) FMA4(accB[i], a[i].z, wb2)
      FMA4(accA[i], a[i].w, wa3) FMA4(accB[i], a[i].w, wb3)
    }
  }

  const float4 bv0 = reinterpret_cast<const float4*>(bias)[2 * j8];
  const float4 bv1 = reinterpret_cast<const float4*>(bias)[2 * j8 + 1];
#pragma unroll
  for (int i = 0; i < 8; ++i) {
    const int row = rowBase + r0 + 16 * i;
    if (row < NN) {
      const float nrm = norm[row];
      float4 o0, o1;
      o0.x = accA[i].x * nrm + bv0.x; o0.y = accA[i].y * nrm + bv0.y;
      o0.z = accA[i].z * nrm + bv0.z; o0.w = accA[i].w * nrm + bv0.w;
      o1.x = accB[i].x * nrm + bv1.x; o1.y = accB[i].y * nrm + bv1.y;
      o1.z = accB[i].z * nrm + bv1.z; o1.w = accB[i].w * nrm + bv1.w;
      o0.x = o0.x > 0.f ? o0.x : 0.2f * o0.x;
      o0.y = o0.y > 0.f ? o0.y : 0.2f * o0.y;
      o0.z = o0.z > 0.f ? o0.z : 0.2f * o0.z;
      o0.w = o0.w > 0.f ? o0.w : 0.2f * o0.w;
      o1.x = o1.x > 0.f ? o1.x : 0.2f * o1.x;
      o1.y = o1.y > 0.f ? o1.y : 0.2f * o1.y;
      o1.z = o1.z > 0.f ? o1.z : 0.2f * o1.z;
      o1.w = o1.w > 0.f ? o1.w : 0.2f * o1.w;
      if (SCALE_OUT) {
        o0.x *= nrm; o0.y *= nrm; o0.z *= nrm; o0.w *= nrm;
        o1.x *= nrm; o1.y *= nrm; o1.z *= nrm; o1.w *= nrm;
      }
      float4* op = reinterpret_cast<float4*>(out + (size_t)row * H + j8 * 8);
      op[0] = o0;
      op[1] = o1;
    }
  }
}

}  // namespace

extern "C" void kernel_launch(void* const* d_in, const int* in_sizes, int n_in,
                              void* d_out, int out_size, void* d_ws, size_t ws_size,
                              hipStream_t stream) {
  float* out = (float*)d_out;                 // OUTPUT IS FP32
  const int nElem = NN * H;                   // 12.8M
  const int mkBl  = (out_size + 255) / 256;

  bool order_ok =
      (n_in == 9 && in_sizes[0] == NN && in_sizes[1] == NE && in_sizes[2] == NE &&
       in_sizes[3] == NN && in_sizes[4] == NN * H && in_sizes[5] == H * H &&
       in_sizes[6] == H && in_sizes[7] == H * H && in_sizes[8] == H);
  if (!order_ok || out_size != nElem) {
    write_marker<<<mkBl, 256, 0, stream>>>(out, out_size,
                                           (out_size != nElem) ? 300.0f : 200.0f);
    return;
  }
  if (ws_size < (size_t)nElem * 4) {
    write_marker<<<mkBl, 256, 0, stream>>>(out, out_size,
                                           2.0f + (float)(ws_size >> 20));
    return;
  }

  const int* node_id = (const int*)d_in[0];
  const int* src     = (const int*)d_in[1];
  const int* dst     = (const int*)d_in[2];
  const float* norm  = (const float*)d_in[3];
  const float* embed = (const float*)d_in[4];
  const float* W1    = (const float*)d_in[5];
  const float* b1    = (const float*)d_in[6];
  const float* W2    = (const float*)d_in[7];
  const float* b2    = (const float*)d_in[8];

  float* agg = (float*)d_ws;                             // 51.2 MB
  float* h1n = out;                                      // d_out holds h1*norm
  int2* rec1 = (int2*)((char*)d_ws + (size_t)nElem * 4); // NE x 8B (8-aligned)
  int* csr2  = (int*)(rec1 + NE);                        // NE
  int* offs  = csr2 + NE;                                // NN+1
  int* cnt   = offs + (NN + 1);                          // NN
  int* bsums = cnt + NN;                                 // 512

  const size_t need_mid =
      (size_t)nElem * 4 + ((size_t)NE + (NN + 1) + NN + 512) * 4;        // ~54.4 MB
  const size_t need_full = need_mid + (size_t)NE * 8;                    // ~59.2 MB

  const int zeroNBl = (NN + 255) / 256;
  const int edgeBl  = (NE + 255) / 256;
  const int gemmBl  = (NN + 127) / 128;  // 782

  if (ws_size >= need_mid) {
    const bool full = (ws_size >= need_full);
    // layout shift for mid tier: rec1 unused; csr2 right after agg
    if (!full) {
      csr2  = (int*)((char*)d_ws + (size_t)nElem * 4);
      offs  = csr2 + NE;
      cnt   = offs + (NN + 1);
      bsums = cnt + NN;
    }

    // ---- build CSR by dst (shared by both layers) ----
    zero_int<<<zeroNBl, 256, 0, stream>>>(cnt, NN);
    hist_dst<<<edgeBl, 256, 0, stream>>>(dst, cnt);
    scan1<<<NBLK_SCAN, SCAN_B, 0, stream>>>(cnt, offs, bsums);
    scan2<<<1, 512, 0, stream>>>(bsums);
    scan3<<<NBLK_SCAN, 256, 0, stream>>>(offs, bsums, cnt);
    if (full)
      fill_csr<true><<<edgeBl, 256, 0, stream>>>(src, dst, node_id, norm, cnt, csr2, rec1);
    else
      fill_csr<false><<<edgeBl, 256, 0, stream>>>(src, dst, node_id, norm, cnt, csr2, nullptr);

    // ---- layer 1 ----
    if (full)
      gather_rec<<<NN / 8, 256, 0, stream>>>(offs, rec1, embed, agg);
    else
      gather_mid_l1<<<NN / 8, 256, 0, stream>>>(offs, csr2, node_id, embed, norm, agg);
    gemm_v3<true><<<gemmBl, 256, 0, stream>>>(agg, W1, norm, b1, h1n);

    // ---- layer 2 ----
    gather_idx<<<NN / 8, 256, 0, stream>>>(offs, csr2, h1n, agg);
    gemm_v3<false><<<gemmBl, 256, 0, stream>>>(agg, W2, norm, b2, out);
    return;
  }

  // ---- bottom-tier fallback: atomic path ----
  const int zeroBl = (nElem / 4 + 255) / 256;
  const int scatBl = (NE * 32 + 255) / 256;

  zero_f4<<<zeroBl, 256, 0, stream>>>((float4*)agg, nElem / 4);
  scatter_l1<<<scatBl, 256, 0, stream>>>(src, dst, node_id, embed, norm, agg);
  row_gemm_act<<<NN, 128, 0, stream>>>(agg, W1, norm, b1, out);

  zero_f4<<<zeroBl, 256, 0, stream>>>((float4*)agg, nElem / 4);
  scatter_l2<<<scatBl, 256, 0, stream>>>(src, dst, out, norm, agg);
  row_gemm_act<<<NN, 128, 0, stream>>>(agg, W2, norm, b2, out);
}